// Round 6
// baseline (270.571 us; speedup 1.0000x reference)
//
#include <hip/hip_runtime.h>

typedef unsigned short u16;
typedef unsigned int u32;
typedef __attribute__((ext_vector_type(8))) short short8;
typedef __attribute__((ext_vector_type(4))) float floatx4;
typedef __attribute__((ext_vector_type(4))) float float4v;

#define B_ 32
#define T_ 168
#define NH_ 32
#define NM_ 64
#define E_ 384
#define HL_ 128
#define FUT_ 24
#define SLOPE_ 0.01f
#define XP_ 80     // x-window stride per batch (u16)
#define HP_ 144    // hbuf stride per batch (u16)
#define TW_ 84     // x-window depth (168 = 2*84)
#define WIH_LP 72  // Wih staging row stride (u16): 512*72 = 36864 u16 fits xwin
#define WHH_LP 136 // Whh staging row stride (u16): 256*136 = 34816 u16 fits xwin
#define CH1_ (-1.4426950408889634f)  // folded into i,f,o gate rows
#define CH2_ (2.8853900817779268f)   // folded into g gate rows

static __device__ __forceinline__ float b2f(u16 u) {
  u32 v = ((u32)u) << 16;
  return __builtin_bit_cast(float, v);
}
static __device__ __forceinline__ u16 f2bf(float f) {
  u32 x = __builtin_bit_cast(u32, f);
  u32 r = (x + 0x7fffu + ((x >> 16) & 1u)) >> 16;
  return (u16)r;
}
static __device__ __forceinline__ float fexp2(float x) { return __builtin_amdgcn_exp2f(x); }
static __device__ __forceinline__ float frcp(float x) { return __builtin_amdgcn_rcpf(x); }
// gates arrive PRE-SCALED by CH1_/CH2_ (folded into weights+bias at staging)
static __device__ __forceinline__ float sigm_pre(float x) { return frcp(1.0f + fexp2(x)); }
static __device__ __forceinline__ float tanh_pre(float x) { return 1.0f - 2.0f * frcp(1.0f + fexp2(x)); }
static __device__ __forceinline__ float tanh_fast(float x) {
  return 1.0f - 2.0f * frcp(1.0f + fexp2(2.8853900817779268f * x));
}
static __device__ __forceinline__ float sel4(floatx4 v, int r) {
  float m0 = (r & 1) ? v[1] : v[0];
  float m1 = (r & 1) ? v[3] : v[2];
  return (r & 2) ? m1 : m0;
}
static __device__ __forceinline__ float lrelu(float x) { return fmaxf(x, SLOPE_ * x); }

// Fused GNN + per-station LSTM + head. Two independent batch-streams (A/B) per
// WG share station weights and one barrier per step (stall amortization).
// Grid: 128 WGs = 32 stations x 4 bgp (8 batches: A = 0..3, B = 4..7). 512 thr.
__launch_bounds__(512, 2)
__global__ void fused_kernel(const float* __restrict__ dm, const float* __restrict__ dh,
                             const int* __restrict__ eidx,
                             const float* __restrict__ Wroot, const float* __restrict__ Wrel,
                             const float* __restrict__ bgnn,
                             const float* __restrict__ Wih, const float* __restrict__ Whh,
                             const float* __restrict__ bih, const float* __restrict__ bhh,
                             const float* __restrict__ Wlin, const float* __restrict__ blin,
                             float* __restrict__ out) {
  const int s = blockIdx.x & 31;
  const int bgp = blockIdx.x >> 5;  // 0..3
  const int tid = threadIdx.x;
  const int w = tid >> 6;
  const int lane = tid & 63;
  const int cm = lane & 15;
  const int q = lane >> 4;
  const int b = cm & 3;
  const int rho = cm >> 2;

  // xwin: weight-staging overlay first, then rolling 84-step x-feature window
  __shared__ __align__(16) u16 xwin[TW_ * 8 * XP_];   // 107520 B
  __shared__ __align__(16) u16 hbuf[2 * 2 * 4 * HP_]; // [stream][p][b][HP_]
  __shared__ float xh_lds[8][T_];
  __shared__ float ag_lds[8][T_];
  __shared__ float wr_s[64], wv_s[64], bg_s[64];
  __shared__ int srcs[E_];
  __shared__ int nsrc, iflag;

  // ---- A: init
  if (tid == 0) { nsrc = 0; iflag = 0; }
  for (int i = tid; i < 2 * 2 * 4 * HP_; i += 512) hbuf[i] = 0;
  __syncthreads();

  // ---- B: int64-vs-int32 edge_index probe
  {
    int odd = 0;
    for (int e = tid; e < E_; e += 512) odd |= eidx[2 * e + 1];
    if (odd) atomicOr(&iflag, 1);
  }
  __syncthreads();
  const bool i32 = iflag != 0;

  // ---- C: in-edges; stage small tensors; bias (with gate-scale folding)
  for (int e = tid; e < E_; e += 512) {
    int se = i32 ? eidx[e] : eidx[2 * e];
    int de = i32 ? eidx[E_ + e] : eidx[2 * E_ + 2 * e];
    if (de == s) { int i = atomicAdd(&nsrc, 1); srcs[i] = se; }
  }
  if (tid < 64) { wr_s[tid] = Wroot[tid]; wv_s[tid] = Wrel[tid]; bg_s[tid] = bgnn[tid]; }
  for (int i = tid; i < 8 * T_; i += 512) {
    int bb = i / T_, t = i % T_;
    xh_lds[bb][t] = dh[((size_t)(bgp * 8 + bb) * T_ + t) * NH_ + s];
  }
  floatx4 bias_init[4];
#pragma unroll
  for (int blk = 0; blk < 4; blk++) {
    const float sc = (blk == 2) ? CH2_ : CH1_;
#pragma unroll
    for (int r = 0; r < 4; r++) {
      const int nb = blk * 128 + w * 16 + q * 4 + r;
      bias_init[blk][r] = (bih[s * 512 + nb] + bhh[s * 512 + nb]) * sc;
    }
  }
  __syncthreads();

  // ---- D: per-(b,t) graph aggregation (avg ~4 in-edges/station)
  const int ns = nsrc;
  for (int i = tid; i < 8 * T_; i += 512) {
    int bb = i / T_, t = i % T_;
    size_t gb = (size_t)(bgp * 8 + bb) * T_ + t;
    float a = 0.f;
    for (int j = 0; j < ns; j++) {
      int sr = srcs[j];
      a += (sr < NH_) ? dh[gb * NH_ + sr] : dm[gb * NM_ + (sr - NH_)];
    }
    ag_lds[bb][t] = a;
  }

  // ---- W: coalesced LDS-staged weight load, 3 fully-unrolled rounds, static Af
  // indices (register residency guaranteed); gate-scale folded in at convert.
  short8 Af[4][6];
  const int nl = w * 16 + cm;
  __syncthreads();
  {  // Round 1: all of Wih (512 rows x 64)
    const float* g = Wih + (size_t)s * 512 * 64;
#pragma unroll
    for (int it = 0; it < 16; it++) {
      int j = tid + it * 512;
      float4v v = *(const float4v*)(g + 4 * j);
      const float sc = (((j >> 4) >> 7) == 2) ? CH2_ : CH1_;
      u16* dst = xwin + (j >> 4) * WIH_LP + (j & 15) * 4;
      dst[0] = f2bf(v[0] * sc); dst[1] = f2bf(v[1] * sc);
      dst[2] = f2bf(v[2] * sc); dst[3] = f2bf(v[3] * sc);
    }
  }
  __syncthreads();
#pragma unroll
  for (int blk = 0; blk < 4; blk++)
#pragma unroll
    for (int kk = 0; kk < 2; kk++)
      Af[blk][kk] = *(const short8*)(xwin + (blk * 128 + nl) * WIH_LP + kk * 32 + q * 8);
  __syncthreads();
  {  // Round 2: Whh rows 0..255 (gate blocks 0,1 -> always CH1_)
    const float* g = Whh + (size_t)s * 512 * 128;
#pragma unroll
    for (int it = 0; it < 16; it++) {
      int j = tid + it * 512;
      float4v v = *(const float4v*)(g + 4 * j);
      u16* dst = xwin + (j >> 5) * WHH_LP + (j & 31) * 4;
      dst[0] = f2bf(v[0] * CH1_); dst[1] = f2bf(v[1] * CH1_);
      dst[2] = f2bf(v[2] * CH1_); dst[3] = f2bf(v[3] * CH1_);
    }
  }
  __syncthreads();
#pragma unroll
  for (int blk = 0; blk < 2; blk++)
#pragma unroll
    for (int kk = 0; kk < 4; kk++)
      Af[blk][2 + kk] = *(const short8*)(xwin + (blk * 128 + nl) * WHH_LP + kk * 32 + q * 8);
  __syncthreads();
  {  // Round 3: Whh rows 256..511 (block 2 -> CH2_, block 3 -> CH1_)
    const float* g = Whh + ((size_t)s * 512 + 256) * 128;
#pragma unroll
    for (int it = 0; it < 16; it++) {
      int j = tid + it * 512;
      float4v v = *(const float4v*)(g + 4 * j);
      const float sc = ((j >> 5) < 128) ? CH2_ : CH1_;
      u16* dst = xwin + (j >> 5) * WHH_LP + (j & 31) * 4;
      dst[0] = f2bf(v[0] * sc); dst[1] = f2bf(v[1] * sc);
      dst[2] = f2bf(v[2] * sc); dst[3] = f2bf(v[3] * sc);
    }
  }
  __syncthreads();
#pragma unroll
  for (int blk = 2; blk < 4; blk++)
#pragma unroll
    for (int kk = 0; kk < 4; kk++)
      Af[blk][2 + kk] = *(const short8*)(xwin + ((blk - 2) * 128 + nl) * WHH_LP + kk * 32 + q * 8);

  // ---- recurrent: 2 chunks x 84 steps; one barrier per step serves BOTH streams
  float cA = 0.f, cB = 0.f;
  floatx4 accNA[4];
#pragma unroll 1
  for (int ch = 0; ch < 2; ch++) {
    const int t0 = ch * TW_;
    __syncthreads();  // xwin free (prev chunk consumed / staging reads done)
    {  // refill x-window: x[t0+i][bb][k] = lrelu(xh*wr + ag*wv + bg)
      const int k = tid & 63;
      const int bb = tid >> 6;
      const float wrk = wr_s[k], wvk = wv_s[k], bgk = bg_s[k];
      u16* xw = xwin + bb * XP_ + k;
#pragma unroll 4
      for (int i = 0; i < TW_; i++) {
        const float xv = xh_lds[bb][t0 + i] * wrk + ag_lds[bb][t0 + i] * wvk + bgk;
        xw[i * (8 * XP_)] = f2bf(lrelu(xv));
      }
    }
    __syncthreads();
    // chunk-head: accNA(t0) and BxB(t0) regs
    short8 BxB0, BxB1;
    {
      short8 BxA0 = *(const short8*)(xwin + b * XP_ + q * 8);
      short8 BxA1 = *(const short8*)(xwin + b * XP_ + 32 + q * 8);
#pragma unroll
      for (int blk = 0; blk < 4; blk++) {
        accNA[blk] = __builtin_amdgcn_mfma_f32_16x16x32_bf16(Af[blk][0], BxA0, bias_init[blk], 0, 0, 0);
        accNA[blk] = __builtin_amdgcn_mfma_f32_16x16x32_bf16(Af[blk][1], BxA1, accNA[blk], 0, 0, 0);
      }
      BxB0 = *(const short8*)(xwin + (b + 4) * XP_ + q * 8);
      BxB1 = *(const short8*)(xwin + (b + 4) * XP_ + 32 + q * 8);
    }
#pragma unroll 2
    for (int i = 0; i < TW_; i++) {
      const int p = i & 1, pn = p ^ 1;
      // stream A h-fragments (post-barrier; latency filled by accNB MFMAs)
      short8 BhA[4];
#pragma unroll
      for (int kk = 0; kk < 4; kk++)
        BhA[kk] = *(const short8*)(hbuf + (p * 4 + b) * HP_ + kk * 32 + q * 8);
      // stream B x-part (independent of barrier data)
      floatx4 aB[4];
#pragma unroll
      for (int blk = 0; blk < 4; blk++) {
        aB[blk] = __builtin_amdgcn_mfma_f32_16x16x32_bf16(Af[blk][0], BxB0, bias_init[blk], 0, 0, 0);
        aB[blk] = __builtin_amdgcn_mfma_f32_16x16x32_bf16(Af[blk][1], BxB1, aB[blk], 0, 0, 0);
      }
      // stream A h-MFMAs
      floatx4 aA[4];
#pragma unroll
      for (int blk = 0; blk < 4; blk++)
        aA[blk] = __builtin_amdgcn_mfma_f32_16x16x32_bf16(Af[blk][2], BhA[0], accNA[blk], 0, 0, 0);
#pragma unroll
      for (int kk = 1; kk < 4; kk++)
#pragma unroll
        for (int blk = 0; blk < 4; blk++)
          aA[blk] = __builtin_amdgcn_mfma_f32_16x16x32_bf16(Af[blk][2 + kk], BhA[kk], aA[blk], 0, 0, 0);
      // stream B h-fragments
      short8 BhB[4];
#pragma unroll
      for (int kk = 0; kk < 4; kk++)
        BhB[kk] = *(const short8*)(hbuf + ((2 + p) * 4 + b) * HP_ + kk * 32 + q * 8);
      // activate A (gates pre-scaled)
      {
        const float gi = sel4(aA[0], rho);
        const float gf = sel4(aA[1], rho);
        const float gg = sel4(aA[2], rho);
        const float go = sel4(aA[3], rho);
        cA = sigm_pre(gf) * cA + sigm_pre(gi) * tanh_pre(gg);
        const float hh = sigm_pre(go) * tanh_fast(cA);
        hbuf[(pn * 4 + b) * HP_ + w * 16 + q * 4 + rho] = f2bf(hh);
      }
      // stream B h-MFMAs
#pragma unroll
      for (int kk = 0; kk < 4; kk++)
#pragma unroll
        for (int blk = 0; blk < 4; blk++)
          aB[blk] = __builtin_amdgcn_mfma_f32_16x16x32_bf16(Af[blk][2 + kk], BhB[kk], aB[blk], 0, 0, 0);
      // prefetch next step's accNA and BxB regs
      if (i + 1 < TW_) {
        short8 BxA0 = *(const short8*)(xwin + (i + 1) * (8 * XP_) + b * XP_ + q * 8);
        short8 BxA1 = *(const short8*)(xwin + (i + 1) * (8 * XP_) + b * XP_ + 32 + q * 8);
#pragma unroll
        for (int blk = 0; blk < 4; blk++) {
          accNA[blk] = __builtin_amdgcn_mfma_f32_16x16x32_bf16(Af[blk][0], BxA0, bias_init[blk], 0, 0, 0);
          accNA[blk] = __builtin_amdgcn_mfma_f32_16x16x32_bf16(Af[blk][1], BxA1, accNA[blk], 0, 0, 0);
        }
        BxB0 = *(const short8*)(xwin + (i + 1) * (8 * XP_) + (b + 4) * XP_ + q * 8);
        BxB1 = *(const short8*)(xwin + (i + 1) * (8 * XP_) + (b + 4) * XP_ + 32 + q * 8);
      }
      // activate B
      {
        const float gi = sel4(aB[0], rho);
        const float gf = sel4(aB[1], rho);
        const float gg = sel4(aB[2], rho);
        const float go = sel4(aB[3], rho);
        cB = sigm_pre(gf) * cB + sigm_pre(gi) * tanh_pre(gg);
        const float hh = sigm_pre(go) * tanh_fast(cB);
        hbuf[((2 + pn) * 4 + b) * HP_ + w * 16 + q * 4 + rho] = f2bf(hh);
      }
      __syncthreads();
    }
  }

  // ---- head: final h in buffer p=0 of each stream
  if (tid < 8 * FUT_) {
    const int bb = tid / FUT_;
    const int f = tid % FUT_;
    const int st = bb >> 2, bl = bb & 3;
    float a = blin[f];
#pragma unroll 8
    for (int k = 0; k < HL_; k++)
      a += b2f(hbuf[(st * 2 * 4 + bl) * HP_ + k]) * Wlin[f * HL_ + k];
    out[((size_t)(bgp * 8 + bb) * NH_ + s) * FUT_ + f] = lrelu(a);
  }
}

extern "C" void kernel_launch(void* const* d_in, const int* in_sizes, int n_in,
                              void* d_out, int out_size, void* d_ws, size_t ws_size,
                              hipStream_t stream) {
  const float* dm = (const float*)d_in[0];
  const float* dh = (const float*)d_in[1];
  const int* eidx = (const int*)d_in[2];
  const float* Wroot = (const float*)d_in[3];
  const float* Wrel = (const float*)d_in[4];
  const float* bgnn = (const float*)d_in[5];
  const float* Wih = (const float*)d_in[6];
  const float* Whh = (const float*)d_in[7];
  const float* bih = (const float*)d_in[8];
  const float* bhh = (const float*)d_in[9];
  const float* Wlin = (const float*)d_in[10];
  const float* blin = (const float*)d_in[11];
  float* out = (float*)d_out;

  fused_kernel<<<128, 512, 0, stream>>>(dm, dh, eidx, Wroot, Wrel, bgnn, Wih, Whh,
                                        bih, bhh, Wlin, blin, out);
}